// Round 3
// baseline (184.734 us; speedup 1.0000x reference)
//
#include <hip/hip_runtime.h>

#define N_ROWS 8192
#define BM 128
#define CHUNK 256
#define BN 64
#define NITER (CHUNK / BN)       // 4
#define NCHUNK (N_ROWS / CHUNK)  // 32

typedef __attribute__((ext_vector_type(8))) short short8;
typedef __attribute__((ext_vector_type(4))) float f32x4;

__device__ __forceinline__ unsigned short f2bf(float x) {
  unsigned int u = __float_as_uint(x);
  unsigned int r = (u + 0x7fffu + ((u >> 16) & 1u)) >> 16;
  return (unsigned short)r;
}

__device__ __forceinline__ float fast_exp2(float x) {
  float r;
  asm("v_exp_f32 %0, %1" : "=v"(r) : "v"(x));
  return r;
}

// Kernel 1: L2-normalize rows, write bf16 plain row-major (128 bf16 = 64 u32 per row).
__global__ __launch_bounds__(256) void knorm(const float* __restrict__ feat,
                                             unsigned int* __restrict__ fn) {
  const int wid = threadIdx.x >> 6;
  const int lane = threadIdx.x & 63;
  const int row = blockIdx.x * 4 + wid;
  const float2 v = *(const float2*)(feat + (size_t)row * 128 + lane * 2);
  float s = v.x * v.x + v.y * v.y;
#pragma unroll
  for (int m = 1; m < 64; m <<= 1) s += __shfl_xor(s, m);
  const float inv = 1.0f / fmaxf(sqrtf(s), 1e-12f);
  fn[row * 64 + lane] = (unsigned int)f2bf(v.x * inv) |
                        ((unsigned int)f2bf(v.y * inv) << 16);
}

// Kernel 2: barrier-free, LDS-free fused bf16 MFMA sim + exp + masked row sums.
// Block = 128 rows x 256 cols; 4 waves, each wave owns 32 rows x 64-col subtiles.
// 8 blocks/CU (launch_bounds 256,8; VGPR must stay <=64) -> 8 waves/SIMD TLP
// hides the serialized L2 B-load latency.
__global__ __launch_bounds__(256, 8) void ksim(const unsigned int* __restrict__ fn,
                                               const float* __restrict__ alphap,
                                               float* __restrict__ posP,
                                               float* __restrict__ totP) {
  const int tid = threadIdx.x;
  const int lane = tid & 63;
  const int wid = tid >> 6;
  const int r0 = blockIdx.x * BM;
  const int c0 = blockIdx.y * CHUNK;
  const float alpha = alphap[0];
  const float KEXP = 20.60992915f;  // log2(e)/TAU

  const char* __restrict__ F = (const char*)fn;

  // A fragments in registers: 2 m-frags x 4 k-steps (wave rows = r0+wid*32 .. +32).
  short8 aR[2][4];
  {
    const char* ar = F + (size_t)(r0 + wid * 32 + (lane & 15)) * 256 + (lane >> 4) * 16;
#pragma unroll
    for (int m = 0; m < 2; m++)
#pragma unroll
      for (int ks = 0; ks < 4; ks++)
        aR[m][ks] = *(const short8*)(ar + m * 16 * 256 + ks * 64);
  }

  float pp[2][4] = {{0.f}}, tp[2][4] = {{0.f}};
  const char* __restrict__ brow = F + (size_t)(c0 + (lane & 15)) * 256 + (lane >> 4) * 16;

#pragma unroll 1
  for (int it = 0; it < NITER; ++it) {
    const char* bb = brow + it * (BN * 256);

    f32x4 acc[2][4];
#pragma unroll
    for (int m = 0; m < 2; m++)
#pragma unroll
      for (int n = 0; n < 4; n++) acc[m][n] = (f32x4){0.f, 0.f, 0.f, 0.f};

#pragma unroll
    for (int ks = 0; ks < 4; ks++) {
      const short8 b0 = *(const short8*)(bb + 0 * 4096 + ks * 64);
      const short8 b1 = *(const short8*)(bb + 1 * 4096 + ks * 64);
      const short8 b2 = *(const short8*)(bb + 2 * 4096 + ks * 64);
      const short8 b3 = *(const short8*)(bb + 3 * 4096 + ks * 64);
#pragma unroll
      for (int m = 0; m < 2; m++) {
        acc[m][0] = __builtin_amdgcn_mfma_f32_16x16x32_bf16(aR[m][ks], b0, acc[m][0], 0, 0, 0);
        acc[m][1] = __builtin_amdgcn_mfma_f32_16x16x32_bf16(aR[m][ks], b1, acc[m][1], 0, 0, 0);
        acc[m][2] = __builtin_amdgcn_mfma_f32_16x16x32_bf16(aR[m][ks], b2, acc[m][2], 0, 0, 0);
        acc[m][3] = __builtin_amdgcn_mfma_f32_16x16x32_bf16(aR[m][ks], b3, acc[m][3], 0, 0, 0);
      }
    }

    // Epilogue: e = 2^(sim*log2e/tau); tot += e (j!=i); pos += e if sim>=alpha.
    const int cb = c0 + it * BN;
#pragma unroll
    for (int m = 0; m < 2; m++) {
      const int grb = r0 + wid * 32 + m * 16;  // fragment row base (16-aligned)
#pragma unroll
      for (int n = 0; n < 4; n++) {
        const int gcb = cb + n * 16;           // fragment col base (16-aligned)
        const f32x4 a = acc[m][n];
        if (grb == gcb) {  // diagonal fragment: per-element self-exclusion
          const int gr0 = (lane >> 4) << 2;
          const int gcl = lane & 15;
#pragma unroll
          for (int r = 0; r < 4; r++) {
            const float e = fast_exp2(a[r] * KEXP);
            const float ev = (gr0 + r == gcl) ? 0.0f : e;
            tp[m][r] += ev;
            pp[m][r] += (a[r] >= alpha) ? ev : 0.0f;
          }
        } else {
#pragma unroll
          for (int r = 0; r < 4; r++) {
            const float e = fast_exp2(a[r] * KEXP);
            tp[m][r] += e;
            pp[m][r] += (a[r] >= alpha) ? e : 0.0f;
          }
        }
      }
    }
  }

  // Reduce across the 16 column-lanes; each wave owns distinct rows -> direct store.
#pragma unroll
  for (int m = 0; m < 2; m++)
#pragma unroll
    for (int r = 0; r < 4; r++) {
      float p = pp[m][r], t = tp[m][r];
#pragma unroll
      for (int msk = 1; msk < 16; msk <<= 1) {
        p += __shfl_xor(p, msk);
        t += __shfl_xor(t, msk);
      }
      if ((lane & 15) == 0) {
        const int row = r0 + wid * 32 + m * 16 + ((lane >> 4) << 2) + r;
        posP[blockIdx.y * N_ROWS + row] = p;
        totP[blockIdx.y * N_ROWS + row] = t;
      }
    }
}

// Kernel 3a: per-row loss term, 128-row blocks -> 64 partial sums.
__global__ __launch_bounds__(128) void kred1(const float* __restrict__ posP,
                                             const float* __restrict__ totP,
                                             float* __restrict__ bp) {
  const int t = threadIdx.x;
  const int row = blockIdx.x * 128 + t;
  float pos = 0.f, tot = 0.f;
#pragma unroll
  for (int c = 0; c < NCHUNK; c++) {
    pos += posP[c * N_ROWS + row];
    tot += totP[c * N_ROWS + row];
  }
  float term = __logf(tot + 2e-10f) - __logf(pos + 1e-10f);
#pragma unroll
  for (int m = 1; m < 64; m <<= 1) term += __shfl_xor(term, m);
  __shared__ float s2[2];
  if ((t & 63) == 0) s2[t >> 6] = term;
  __syncthreads();
  if (t == 0) bp[blockIdx.x] = s2[0] + s2[1];
}

// Kernel 3b: final mean.
__global__ void kred2(const float* __restrict__ bp, float* __restrict__ out) {
  const int l = threadIdx.x;
  float v = bp[l];
#pragma unroll
  for (int m = 1; m < 64; m <<= 1) v += __shfl_xor(v, m);
  if (l == 0) out[0] = v * (1.0f / 8192.0f);
}

extern "C" void kernel_launch(void* const* d_in, const int* in_sizes, int n_in,
                              void* d_out, int out_size, void* d_ws, size_t ws_size,
                              hipStream_t stream) {
  const float* feat = (const float*)d_in[0];
  const float* alphap = (const float*)d_in[1];
  char* ws = (char*)d_ws;
  unsigned int* fn = (unsigned int*)ws;                     // 2 MB bf16 row-major
  float* posP = (float*)(ws + (2u << 20));                  // 1 MB  (32 chunks x 8192)
  float* totP = (float*)(ws + (3u << 20));                  // 1 MB
  float* bp = (float*)(ws + (4u << 20));                    // 256 B
  float* out = (float*)d_out;

  knorm<<<dim3(N_ROWS / 4), dim3(256), 0, stream>>>(feat, fn);
  ksim<<<dim3(N_ROWS / BM, NCHUNK), dim3(256), 0, stream>>>(fn, alphap, posP, totP);
  kred1<<<dim3(N_ROWS / 128), dim3(128), 0, stream>>>(posP, totP, bp);
  kred2<<<dim3(1), dim3(64), 0, stream>>>(bp, out);
}

// Round 4
// 69.913 us; speedup vs baseline: 2.6423x; 2.6423x over previous
//
#include <hip/hip_runtime.h>

#define N_ROWS 8192
#define BM 128
#define CHUNK 512
#define BN 64
#define NITER (CHUNK / BN)       // 8
#define NCHUNK (N_ROWS / CHUNK)  // 16
#define NPART (NCHUNK * 2)       // 32 column-partials per row (2 wc halves)
#define KEXP 20.60992915f        // log2(e)/TAU

typedef __attribute__((ext_vector_type(8))) short short8;
typedef __attribute__((ext_vector_type(4))) float f32x4;

__device__ __forceinline__ void gload_lds16(const void* g, void* l) {
  __builtin_amdgcn_global_load_lds(
      (const __attribute__((address_space(1))) void*)g,
      (__attribute__((address_space(3))) void*)l, 16, 0, 0);
}

__device__ __forceinline__ unsigned short f2bf(float x) {
  unsigned int u = __float_as_uint(x);
  unsigned int r = (u + 0x7fffu + ((u >> 16) & 1u)) >> 16;
  return (unsigned short)r;
}

__device__ __forceinline__ float fast_exp2(float x) {
  float r;
  asm("v_exp_f32 %0, %1" : "=v"(r) : "v"(x));
  return r;
}

// Kernel 1: L2-normalize rows; write TWO bf16 arrays, both 16B-chunk-swizzled
// (chunk ^= row&7): fnA scaled by log2(e)/tau (MFMA A operand), fnB unscaled.
__global__ __launch_bounds__(256) void knorm(const float* __restrict__ feat,
                                             unsigned int* __restrict__ fnA,
                                             unsigned int* __restrict__ fnB) {
  const int wid = threadIdx.x >> 6;
  const int lane = threadIdx.x & 63;
  const int row = blockIdx.x * 4 + wid;
  const float2 v = *(const float2*)(feat + (size_t)row * 128 + lane * 2);
  float s = v.x * v.x + v.y * v.y;
#pragma unroll
  for (int m = 1; m < 64; m <<= 1) s += __shfl_xor(s, m);
  const float inv = 1.0f / fmaxf(sqrtf(s), 1e-12f);
  const float x = v.x * inv, y = v.y * inv;
  const int idx = row * 64 + ((lane >> 2) ^ (row & 7)) * 4 + (lane & 3);
  fnB[idx] = (unsigned int)f2bf(x) | ((unsigned int)f2bf(y) << 16);
  fnA[idx] = (unsigned int)f2bf(x * KEXP) | ((unsigned int)f2bf(y * KEXP) << 16);
}

// Kernel 2: fused sim+exp+masked-sums. Block = 128 rows x 512 cols, 4 waves in
// 2x2; wave tile 64x32 (m=4: halves LDS B reads per output). A frags from
// global (L2-resident) into regs once; B double-buffered in 32KB LDS.
__global__ __launch_bounds__(256, 3) void ksim(const unsigned int* __restrict__ fnA,
                                               const unsigned int* __restrict__ fnB,
                                               const float* __restrict__ alphap,
                                               float* __restrict__ posP,
                                               float* __restrict__ totP) {
  __shared__ __align__(16) char smem[32768];  // B dbuf: 2 x 16KB
  const int tid = threadIdx.x;
  const int lane = tid & 63;
  const int wid = tid >> 6;
  const int wr = wid >> 1, wc = wid & 1;
  const int r0 = blockIdx.x * BM;
  const int c0 = blockIdx.y * CHUNK;
  const float alphaK = alphap[0] * KEXP;

  const char* __restrict__ FA = (const char*)fnA;
  const char* __restrict__ FB = (const char*)fnB;

  // A fragments: 4 m-frags x 4 k-steps, swizzled read from global.
  short8 aR[4][4];
#pragma unroll
  for (int m = 0; m < 4; m++) {
    const int r = r0 + wr * 64 + m * 16 + (lane & 15);
#pragma unroll
    for (int ks = 0; ks < 4; ks++) {
      const int ch = (ks * 4 + (lane >> 4)) ^ (r & 7);
      aR[m][ks] = *(const short8*)(FA + (size_t)r * 256 + ch * 16);
    }
  }

  // Stage B tile it=0 (linear 16KB copy of pre-swizzled rows).
  {
    const char* g = FB + (size_t)(c0 + wid * 16 + (lane >> 4)) * 256 + (lane & 15) * 16;
    char* l = smem + wid * 4096;
#pragma unroll
    for (int s = 0; s < 4; s++) gload_lds16(g + s * 1024, l + s * 1024);
  }
  __syncthreads();

  float pp[4][4] = {{0.f}}, tp[4][4] = {{0.f}};
  int cur = 0;

#pragma unroll 1
  for (int it = 0; it < NITER; ++it) {
    if (it + 1 < NITER) {  // prefetch next B tile into other buffer
      const char* g = FB + (size_t)(c0 + (it + 1) * BN + wid * 16 + (lane >> 4)) * 256 + (lane & 15) * 16;
      char* l = smem + (cur ^ 1) * 16384 + wid * 4096;
#pragma unroll
      for (int s = 0; s < 4; s++) gload_lds16(g + s * 1024, l + s * 1024);
    }

    f32x4 acc[4][2];
#pragma unroll
    for (int m = 0; m < 4; m++)
#pragma unroll
      for (int n = 0; n < 2; n++) acc[m][n] = (f32x4){0.f, 0.f, 0.f, 0.f};

    const char* Bb = smem + cur * 16384;
#pragma unroll
    for (int ks = 0; ks < 4; ks++) {
      const int rB0 = wc * 32 + (lane & 15);
      const int ch = (ks * 4 + (lane >> 4)) ^ (lane & 7);
      const short8 b0 = *(const short8*)(Bb + rB0 * 256 + ch * 16);
      const short8 b1 = *(const short8*)(Bb + (rB0 + 16) * 256 + ch * 16);
#pragma unroll
      for (int m = 0; m < 4; m++) {
        acc[m][0] = __builtin_amdgcn_mfma_f32_16x16x32_bf16(aR[m][ks], b0, acc[m][0], 0, 0, 0);
        acc[m][1] = __builtin_amdgcn_mfma_f32_16x16x32_bf16(aR[m][ks], b1, acc[m][1], 0, 0, 0);
      }
    }

    // Epilogue: a = sim*log2e/tau (pre-scaled). e = 2^a; tot += e; pos += e if a>=alphaK.
    const int cb = c0 + it * BN;
#pragma unroll
    for (int m = 0; m < 4; m++) {
      const int grb = r0 + wr * 64 + m * 16;
#pragma unroll
      for (int n = 0; n < 2; n++) {
        const int gcb = cb + wc * 32 + n * 16;
        const f32x4 a = acc[m][n];
        if (grb == gcb) {  // diagonal fragment: self-exclusion
          const int gr0 = (lane >> 4) << 2;
          const int gcl = lane & 15;
#pragma unroll
          for (int r = 0; r < 4; r++) {
            const float e = fast_exp2(a[r]);
            const float ev = (gr0 + r == gcl) ? 0.0f : e;
            tp[m][r] += ev;
            pp[m][r] += (a[r] >= alphaK) ? ev : 0.0f;
          }
        } else {
#pragma unroll
          for (int r = 0; r < 4; r++) {
            const float e = fast_exp2(a[r]);
            tp[m][r] += e;
            pp[m][r] += (a[r] >= alphaK) ? e : 0.0f;
          }
        }
      }
    }
    __syncthreads();
    cur ^= 1;
  }

  // 16-col-lane reduce; store per (chunk, wc) partial — no cross-wave combine.
#pragma unroll
  for (int m = 0; m < 4; m++)
#pragma unroll
    for (int r = 0; r < 4; r++) {
      float p = pp[m][r], t = tp[m][r];
#pragma unroll
      for (int msk = 1; msk < 16; msk <<= 1) {
        p += __shfl_xor(p, msk);
        t += __shfl_xor(t, msk);
      }
      if ((lane & 15) == 0) {
        const int row = r0 + wr * 64 + m * 16 + ((lane >> 4) << 2) + r;
        const int part = blockIdx.y * 2 + wc;
        posP[part * N_ROWS + row] = p;
        totP[part * N_ROWS + row] = t;
      }
    }
}

// Kernel 3a: per-row loss term, 128-row blocks -> 64 partial sums.
__global__ __launch_bounds__(128) void kred1(const float* __restrict__ posP,
                                             const float* __restrict__ totP,
                                             float* __restrict__ bp) {
  const int t = threadIdx.x;
  const int row = blockIdx.x * 128 + t;
  float pos = 0.f, tot = 0.f;
#pragma unroll
  for (int c = 0; c < NPART; c++) {
    pos += posP[c * N_ROWS + row];
    tot += totP[c * N_ROWS + row];
  }
  float term = __logf(tot + 2e-10f) - __logf(pos + 1e-10f);
#pragma unroll
  for (int m = 1; m < 64; m <<= 1) term += __shfl_xor(term, m);
  __shared__ float s2[2];
  if ((t & 63) == 0) s2[t >> 6] = term;
  __syncthreads();
  if (t == 0) bp[blockIdx.x] = s2[0] + s2[1];
}

// Kernel 3b: final mean.
__global__ void kred2(const float* __restrict__ bp, float* __restrict__ out) {
  const int l = threadIdx.x;
  float v = bp[l];
#pragma unroll
  for (int m = 1; m < 64; m <<= 1) v += __shfl_xor(v, m);
  if (l == 0) out[0] = v * (1.0f / 8192.0f);
}

extern "C" void kernel_launch(void* const* d_in, const int* in_sizes, int n_in,
                              void* d_out, int out_size, void* d_ws, size_t ws_size,
                              hipStream_t stream) {
  const float* feat = (const float*)d_in[0];
  const float* alphap = (const float*)d_in[1];
  char* ws = (char*)d_ws;
  unsigned int* fnA = (unsigned int*)ws;                    // 2 MB bf16 swizzled, x log2e/tau
  unsigned int* fnB = (unsigned int*)(ws + (2u << 20));     // 2 MB bf16 swizzled
  float* posP = (float*)(ws + (4u << 20));                  // 1 MB (32 x 8192)
  float* totP = (float*)(ws + (5u << 20));                  // 1 MB
  float* bp = (float*)(ws + (6u << 20));                    // 256 B
  float* out = (float*)d_out;

  knorm<<<dim3(N_ROWS / 4), dim3(256), 0, stream>>>(feat, fnA, fnB);
  ksim<<<dim3(N_ROWS / BM, NCHUNK), dim3(256), 0, stream>>>(fnA, fnB, alphap, posP, totP);
  kred1<<<dim3(N_ROWS / 128), dim3(128), 0, stream>>>(posP, totP, bp);
  kred2<<<dim3(1), dim3(64), 0, stream>>>(bp, out);
}